// Round 2
// baseline (472.248 us; speedup 1.0000x reference)
//
#include <hip/hip_runtime.h>

// DistMult edge score: out[e] = sum_d node_emb[src[e]][d] * rel_emb[e][d] * node_emb[dst[e]][d]
// N_NODES = 100000, N_EDGES = 600000, DIM = 128, fp32, int32 indices.
//
// Strategy: memory-bound gather + stream.
//  - 32-lane group per 4 edges (float4/lane covers one 128-float row).
//  - All 8 index loads + 12x16B vector loads issued before any use: 4x the
//    memory-level parallelism of the 1-edge-per-group version.
//  - rel_emb is 307 MB streamed with ZERO reuse -> nontemporal loads so it
//    doesn't evict node_emb (51 MB, L3-resident, gathered 1.2M times).
//  - out stores nontemporal (never re-read).
//  - 4 reductions share butterfly steps: 9 shuffles instead of 20, same
//    per-edge pairing tree (bit-identical numerics to plain butterfly).

#define DIM 128
#define U 4                   // edges per 32-lane group
#define GROUPS 8              // 32-lane groups per 256-thread block
#define EDGES_PER_BLOCK (U * GROUPS)   // 32

typedef float f4 __attribute__((ext_vector_type(4)));

__global__ __launch_bounds__(256) void distmult_score_kernel(
    const float* __restrict__ node_emb,
    const float* __restrict__ rel_emb,
    const int*   __restrict__ src,
    const int*   __restrict__ dst,
    float*       __restrict__ out,
    int E)
{
    const int tid  = threadIdx.x;      // 0..255
    const int grp  = tid >> 5;         // 0..7
    const int lane = tid & 31;         // 0..31

    const int e0 = (blockIdx.x * GROUPS + grp) * U;
    if (e0 >= E) return;               // uniform across each 32-lane group

    if (e0 + U <= E) {
        // ---- fast path: 4 whole edges per group (always taken: 600000 % 32 == 0)
        int s[U], d[U];
        #pragma unroll
        for (int u = 0; u < U; ++u) {
            s[u] = src[e0 + u];
            d[u] = dst[e0 + u];
        }

        // rel loads are independent of the index loads -> issue first.
        f4 r[U];
        #pragma unroll
        for (int u = 0; u < U; ++u) {
            const f4* rp = (const f4*)(rel_emb + (size_t)(e0 + u) * DIM);
            r[u] = __builtin_nontemporal_load(rp + lane);
        }

        f4 h[U], t[U];
        #pragma unroll
        for (int u = 0; u < U; ++u) {
            const f4* hp = (const f4*)(node_emb + (size_t)s[u] * DIM);
            const f4* tp = (const f4*)(node_emb + (size_t)d[u] * DIM);
            h[u] = hp[lane];
            t[u] = tp[lane];
        }

        float v[U];
        #pragma unroll
        for (int u = 0; u < U; ++u) {
            v[u] = h[u].x * r[u].x * t[u].x
                 + h[u].y * r[u].y * t[u].y
                 + h[u].z * r[u].z * t[u].z
                 + h[u].w * r[u].w * t[u].w;
        }

        // ---- shared butterfly: 4 reductions in 9 shuffles.
        // fold across lane^16 for each edge
        #pragma unroll
        for (int u = 0; u < U; ++u)
            v[u] += __shfl_xor(v[u], 16, 32);
        // pack edge pairs into lane halves
        float a = (lane & 16) ? v[1] : v[0];   // lanes 0-15: e0,   16-31: e0+1
        float b = (lane & 16) ? v[3] : v[2];   // lanes 0-15: e0+2, 16-31: e0+3
        a += __shfl_xor(a, 8, 32);
        b += __shfl_xor(b, 8, 32);
        float c = (lane & 8) ? b : a;          // 8-lane owners: e0, e0+2, e0+1, e0+3
        c += __shfl_xor(c, 4, 32);
        c += __shfl_xor(c, 2, 32);
        c += __shfl_xor(c, 1, 32);
        // owner lanes: 0 -> e0, 8 -> e0+2, 16 -> e0+1, 24 -> e0+3
        if ((lane & 7) == 0) {
            int u;
            if      (lane == 0)  u = 0;
            else if (lane == 8)  u = 2;
            else if (lane == 16) u = 1;
            else                 u = 3;
            __builtin_nontemporal_store(c, out + e0 + u);
        }
    } else {
        // ---- tail path (unused for E=600000, kept for safety)
        for (int u = 0; u < U; ++u) {
            const int e = e0 + u;
            if (e >= E) break;
            const int s = src[e];
            const int d = dst[e];
            const f4* hp = (const f4*)(node_emb + (size_t)s * DIM);
            const f4* tp = (const f4*)(node_emb + (size_t)d * DIM);
            const f4* rp = (const f4*)(rel_emb  + (size_t)e * DIM);
            const f4 h = hp[lane];
            const f4 r = rp[lane];
            const f4 t = tp[lane];
            float v = h.x * r.x * t.x + h.y * r.y * t.y
                    + h.z * r.z * t.z + h.w * r.w * t.w;
            #pragma unroll
            for (int off = 16; off > 0; off >>= 1)
                v += __shfl_xor(v, off, 32);
            if (lane == 0) out[e] = v;
        }
    }
}

extern "C" void kernel_launch(void* const* d_in, const int* in_sizes, int n_in,
                              void* d_out, int out_size, void* d_ws, size_t ws_size,
                              hipStream_t stream) {
    const float* node_emb = (const float*)d_in[0];
    const float* rel_emb  = (const float*)d_in[1];
    const int*   src      = (const int*)d_in[2];
    const int*   dst      = (const int*)d_in[3];
    float*       out      = (float*)d_out;

    const int E = in_sizes[2];  // 600000 edges

    const int grid = (E + EDGES_PER_BLOCK - 1) / EDGES_PER_BLOCK;
    distmult_score_kernel<<<grid, 256, 0, stream>>>(node_emb, rel_emb, src, dst, out, E);
}

// Round 4
// 470.763 us; speedup vs baseline: 1.0032x; 1.0032x over previous
//
#include <hip/hip_runtime.h>

// DistMult edge score: out[e] = sum_d node_emb[src[e]][d] * rel_emb[e][d] * node_emb[dst[e]][d]
// N_NODES = 100000, N_EDGES = 600000, DIM = 128, fp32, int32 indices.
//
// Strategy: memory-bound gather + stream.
//  - 32-lane group per 2 edges (float4/lane covers one 128-float row).
//    U=2 doubles memory-level parallelism vs 1-edge/group while keeping
//    live VGPRs ~50 -> still 8 waves/SIMD (U=4 cost occupancy, regressed).
//  - rel_emb is 307 MB streamed with ZERO reuse -> nontemporal loads keep it
//    from evicting node_emb rows (51 MB, L3-resident, gathered 1.2M times).
//  - out stores nontemporal (never re-read).
//  - 2 reductions share butterfly steps: 6 shuffles instead of 10, same
//    per-edge pairing tree (bit-identical numerics to plain butterfly).

#define DIM 128
#define U 2                   // edges per 32-lane group
#define GROUPS 8              // 32-lane groups per 256-thread block
#define EDGES_PER_BLOCK (U * GROUPS)   // 16

typedef float f4 __attribute__((ext_vector_type(4)));

__global__ __launch_bounds__(256) void distmult_score_kernel(
    const float* __restrict__ node_emb,
    const float* __restrict__ rel_emb,
    const int*   __restrict__ src,
    const int*   __restrict__ dst,
    float*       __restrict__ out,
    int E)
{
    const int tid  = threadIdx.x;      // 0..255
    const int grp  = tid >> 5;         // 0..7
    const int lane = tid & 31;         // 0..31

    const int e0 = (blockIdx.x * GROUPS + grp) * U;
    if (e0 >= E) return;               // uniform across each 32-lane group

    if (e0 + U <= E) {
        // ---- fast path (always taken: 600000 % 16 == 0)
        int s[U], d[U];
        #pragma unroll
        for (int u = 0; u < U; ++u) {
            s[u] = src[e0 + u];
            d[u] = dst[e0 + u];
        }

        // rel loads are independent of the index loads -> issue early.
        f4 r[U];
        #pragma unroll
        for (int u = 0; u < U; ++u) {
            const f4* rp = (const f4*)(rel_emb + (size_t)(e0 + u) * DIM);
            r[u] = __builtin_nontemporal_load(rp + lane);
        }

        f4 h[U], t[U];
        #pragma unroll
        for (int u = 0; u < U; ++u) {
            const f4* hp = (const f4*)(node_emb + (size_t)s[u] * DIM);
            const f4* tp = (const f4*)(node_emb + (size_t)d[u] * DIM);
            h[u] = hp[lane];
            t[u] = tp[lane];
        }

        float v[U];
        #pragma unroll
        for (int u = 0; u < U; ++u) {
            v[u] = h[u].x * r[u].x * t[u].x
                 + h[u].y * r[u].y * t[u].y
                 + h[u].z * r[u].z * t[u].z
                 + h[u].w * r[u].w * t[u].w;
        }

        // ---- shared butterfly: 2 reductions in 6 shuffles.
        #pragma unroll
        for (int u = 0; u < U; ++u)
            v[u] += __shfl_xor(v[u], 16, 32);
        // lanes 0-15 carry e0, lanes 16-31 carry e0+1
        float a = (lane & 16) ? v[1] : v[0];
        a += __shfl_xor(a, 8, 32);
        a += __shfl_xor(a, 4, 32);
        a += __shfl_xor(a, 2, 32);
        a += __shfl_xor(a, 1, 32);
        // owner lanes: 0 -> e0, 16 -> e0+1
        if ((lane & 15) == 0)
            __builtin_nontemporal_store(a, out + e0 + (lane >> 4));
    } else {
        // ---- tail path (unused for E=600000, kept for safety)
        for (int u = 0; u < U; ++u) {
            const int e = e0 + u;
            if (e >= E) break;
            const int s = src[e];
            const int d = dst[e];
            const f4* hp = (const f4*)(node_emb + (size_t)s * DIM);
            const f4* tp = (const f4*)(node_emb + (size_t)d * DIM);
            const f4* rp = (const f4*)(rel_emb  + (size_t)e * DIM);
            const f4 h = hp[lane];
            const f4 r = rp[lane];
            const f4 t = tp[lane];
            float v = h.x * r.x * t.x + h.y * r.y * t.y
                    + h.z * r.z * t.z + h.w * r.w * t.w;
            #pragma unroll
            for (int off = 16; off > 0; off >>= 1)
                v += __shfl_xor(v, off, 32);
            if (lane == 0) out[e] = v;
        }
    }
}

extern "C" void kernel_launch(void* const* d_in, const int* in_sizes, int n_in,
                              void* d_out, int out_size, void* d_ws, size_t ws_size,
                              hipStream_t stream) {
    const float* node_emb = (const float*)d_in[0];
    const float* rel_emb  = (const float*)d_in[1];
    const int*   src      = (const int*)d_in[2];
    const int*   dst      = (const int*)d_in[3];
    float*       out      = (float*)d_out;

    const int E = in_sizes[2];  // 600000 edges

    const int grid = (E + EDGES_PER_BLOCK - 1) / EDGES_PER_BLOCK;
    distmult_score_kernel<<<grid, 256, 0, stream>>>(node_emb, rel_emb, src, dst, out, E);
}

// Round 5
// 464.431 us; speedup vs baseline: 1.0168x; 1.0136x over previous
//
#include <hip/hip_runtime.h>

// DistMult edge score: out[e] = sum_d node_emb[src[e]][d] * rel_emb[e][d] * node_emb[dst[e]][d]
// N_NODES = 100000, N_EDGES = 600000, DIM = 128, fp32, int32 indices.
//
// Strategy: persistent grid + software pipeline (latency-bound gather fix).
//  - 32-lane group per edge, float4/lane = one 128-float row.
//  - 2048 blocks x 256 threads = 16384 groups = exactly full residency
//    (256 CU x 32 waves). Each group strides over edges (stride 16384).
//  - 2-stage pipeline: idx loads prefetched 2 iterations ahead; rel row and
//    both node-row gathers prefetched 1 iteration ahead. The idx->gather
//    dependency chain (2x ~200-900cy) is exposed only in the prologue;
//    in steady state every load has a full iteration of slack.
//  - NO nontemporal flags: R2/R4 showed nt-flagged streams regress ~15%
//    (bypassing L2/L3 defeats TCC line aggregation on gfx950).

#define DIM 128
#define GROUPS 8            // 32-lane groups per 256-thread block
#define NBLOCKS 2048

typedef float f4 __attribute__((ext_vector_type(4)));

__global__ __launch_bounds__(256) void distmult_score_kernel(
    const float* __restrict__ node_emb,
    const float* __restrict__ rel_emb,
    const int*   __restrict__ src,
    const int*   __restrict__ dst,
    float*       __restrict__ out,
    int E)
{
    const int tid  = threadIdx.x;      // 0..255
    const int grp  = tid >> 5;         // 0..7
    const int lane = tid & 31;         // 0..31

    const int NG = gridDim.x * GROUPS;       // total 32-lane groups (16384)
    int e0 = blockIdx.x * GROUPS + grp;      // current edge
    if (e0 >= E) return;                     // uniform per group

    // ---- prologue: fill the pipeline for edge e0 (chain exposed once)
    int s0 = src[e0];
    int d0 = dst[e0];
    f4 r0 = ((const f4*)(rel_emb + (size_t)e0 * DIM))[lane];
    f4 h0 = ((const f4*)(node_emb + (size_t)s0 * DIM))[lane];
    f4 t0 = ((const f4*)(node_emb + (size_t)d0 * DIM))[lane];

    int e1 = e0 + NG;
    bool m1 = (e1 < E);
    int s1 = 0, d1 = 0;
    if (m1) { s1 = src[e1]; d1 = dst[e1]; }

    while (true) {
        // ---- issue next iteration's row loads (idx already resolved last iter)
        f4 r1, h1, t1;
        if (m1) {
            r1 = ((const f4*)(rel_emb + (size_t)e1 * DIM))[lane];
            h1 = ((const f4*)(node_emb + (size_t)s1 * DIM))[lane];
            t1 = ((const f4*)(node_emb + (size_t)d1 * DIM))[lane];
        }
        // ---- prefetch idx two iterations ahead
        const int e2 = e1 + NG;
        const bool m2 = m1 && (e2 < E);
        int s2 = 0, d2 = 0;
        if (m2) { s2 = src[e2]; d2 = dst[e2]; }

        // ---- compute current edge (r0/h0/t0 were issued a full iter ago)
        float v = h0.x * r0.x * t0.x
                + h0.y * r0.y * t0.y
                + h0.z * r0.z * t0.z
                + h0.w * r0.w * t0.w;
        #pragma unroll
        for (int off = 16; off > 0; off >>= 1)
            v += __shfl_xor(v, off, 32);
        if (lane == 0) out[e0] = v;

        if (!m1) break;
        // ---- rotate pipeline registers
        e0 = e1; r0 = r1; h0 = h1; t0 = t1;
        e1 = e2; s1 = s2; d1 = d2; m1 = m2;
    }
}

extern "C" void kernel_launch(void* const* d_in, const int* in_sizes, int n_in,
                              void* d_out, int out_size, void* d_ws, size_t ws_size,
                              hipStream_t stream) {
    const float* node_emb = (const float*)d_in[0];
    const float* rel_emb  = (const float*)d_in[1];
    const int*   src      = (const int*)d_in[2];
    const int*   dst      = (const int*)d_in[3];
    float*       out      = (float*)d_out;

    const int E = in_sizes[2];  // 600000 edges

    distmult_score_kernel<<<NBLOCKS, 256, 0, stream>>>(node_emb, rel_emb, src, dst, out, E);
}

// Round 6
// 458.775 us; speedup vs baseline: 1.0294x; 1.0123x over previous
//
#include <hip/hip_runtime.h>

// DistMult edge score: out[e] = sum_d node_emb[src[e]][d] * rel_emb[e][d] * node_emb[dst[e]][d]
// N_NODES = 100000, N_EDGES = 600000, DIM = 128, all fp32, indices int32.
//
// Strategy: memory-bound gather + stream. Half-wave (32 lanes) per edge,
// float4 per lane (32 * 4 = 128 floats = one row). Shuffle-reduce within the
// 32-lane group. Block 256 = 8 edges/block.
//
// Session ledger (measured, MI355X):
//   this kernel:                458.0 us   <- best
//   U=4 edges/group + NT:       472.2 us   (nt bypass defeats TCC aggregation)
//   U=2 edges/group + NT:       470.8 us
//   persistent + 2-stage pipe:  464.4 us   (latency-hiding not the lever)
// Timed window = ~370 us harness poison fills (83% HBM peak, at ceiling)
// + ~88 us kernel slice. Slice floor: 366 MB compulsory HBM (~57 us) +
// ~614 MB random 512B L3 gathers -> ~11 TB/s TCC aggregate. L3 gather
// throughput-bound; MLP / cache-bypass / pipelining all measured null.

#define DIM 128
#define EDGES_PER_BLOCK 8

__global__ __launch_bounds__(256) void distmult_score_kernel(
    const float* __restrict__ node_emb,
    const float* __restrict__ rel_emb,
    const int*   __restrict__ src,
    const int*   __restrict__ dst,
    float*       __restrict__ out,
    int E)
{
    const int tid    = threadIdx.x;       // 0..255
    const int half   = tid >> 5;          // 0..7 : which edge within block
    const int lane32 = tid & 31;          // 0..31 : float4 slot within row

    const int e = blockIdx.x * EDGES_PER_BLOCK + half;
    if (e >= E) return;                   // uniform across each 32-lane group

    const int s = src[e];
    const int d = dst[e];

    const float4* __restrict__ hp = (const float4*)(node_emb + (long long)s * DIM);
    const float4* __restrict__ tp = (const float4*)(node_emb + (long long)d * DIM);
    const float4* __restrict__ rp = (const float4*)(rel_emb  + (long long)e * DIM);

    const float4 h = hp[lane32];
    const float4 r = rp[lane32];
    const float4 t = tp[lane32];

    float v = h.x * r.x * t.x
            + h.y * r.y * t.y
            + h.z * r.z * t.z
            + h.w * r.w * t.w;

    // Reduce across the 32-lane half-wave (width=32 keeps groups separate).
    #pragma unroll
    for (int off = 16; off > 0; off >>= 1)
        v += __shfl_xor(v, off, 32);

    if (lane32 == 0) out[e] = v;
}

extern "C" void kernel_launch(void* const* d_in, const int* in_sizes, int n_in,
                              void* d_out, int out_size, void* d_ws, size_t ws_size,
                              hipStream_t stream) {
    const float* node_emb = (const float*)d_in[0];
    const float* rel_emb  = (const float*)d_in[1];
    const int*   src      = (const int*)d_in[2];
    const int*   dst      = (const int*)d_in[3];
    float*       out      = (float*)d_out;

    const int E = in_sizes[2];  // 600000 edges

    const int grid = (E + EDGES_PER_BLOCK - 1) / EDGES_PER_BLOCK;
    distmult_score_kernel<<<grid, 256, 0, stream>>>(node_emb, rel_emb, src, dst, out, E);
}